// Round 1
// baseline (768.258 us; speedup 1.0000x reference)
//
#include <hip/hip_runtime.h>

// VQ-VAE nearest-code lookup, fused GEMM+argmin, fp32 (no fp32 MFMA on CDNA4).
// N=65536 tokens, K=1024 codes, D=256.
// out layout (flat float32): values[N*D] | indices[N] (as float) | vectors[N*D]

constexpr int N_TOK = 65536;
constexpr int KC    = 1024;
constexpr int D     = 256;
constexpr int D4    = D / 4;          // 64 float4 per row

constexpr int BM = 64;                // rows per block
constexpr int BN = 256;               // codes per chunk
constexpr int BK = 32;                // dims per B sub-stage
constexpr int NCHUNK = KC / BN;       // 4
constexpr int NSUB   = D / BK;        // 8

constexpr size_t VAL_OFF = 0;
constexpr size_t IDX_OFF = (size_t)N_TOK * D;        // 16777216
constexpr size_t VEC_OFF = IDX_OFF + N_TOK;          // 16842752

__global__ __launch_bounds__(256)
void vq_sqr_kernel(const float* __restrict__ w, float* __restrict__ sqr) {
    int k = blockIdx.x * blockDim.x + threadIdx.x;
    if (k >= KC) return;
    const float4* w4 = (const float4*)w;
    float s = 0.f;
#pragma unroll 8
    for (int i = 0; i < D4; ++i) {
        float4 v = w4[(size_t)k * D4 + i];
        s += v.x * v.x + v.y * v.y + v.z * v.z + v.w * v.w;
    }
    sqr[k] = s;
}

__global__ __launch_bounds__(256, 1)
void vq_main_kernel(const float* __restrict__ input,
                    const float* __restrict__ weight,
                    const float* __restrict__ sqr,
                    float* __restrict__ out) {
    // LDS: 64K + 32K + 8.25K + 8.25K + 0.25K ~= 113 KB -> 1 block/CU
    __shared__ float As[D][BM];           // A transposed: As[d][row]
    __shared__ float Bs[BK][BN];          // B transposed: Bs[d][code]
    __shared__ float red_sc[BM][33];      // +1 pad: conflict-free reduce
    __shared__ int   red_ix[BM][33];
    __shared__ int   fin_ix[BM];

    const int tid      = threadIdx.x;
    const int row_grp  = tid & 7;         // 8 groups x 8 rows = 64 rows
    const int code_grp = tid >> 3;        // 32 groups x 8 codes = 256 codes
    const int row0     = blockIdx.x * BM;

    // ---- stage A transposed, once ----
    // lane -> consecutive r: LDS writes conflict-free (2-way max, free).
    // global loads per-lane stride 1KB; block tile 64KB is L1/L2-friendly.
    {
        const float4* in4 = (const float4*)input;
#pragma unroll
        for (int k = 0; k < (BM * D4) / 256; ++k) {     // 16 iters
            int i  = tid + k * 256;
            int r  = i & (BM - 1);
            int dq = i >> 6;
            float4 v = in4[(size_t)(row0 + r) * D4 + dq];
            As[dq * 4 + 0][r] = v.x;
            As[dq * 4 + 1][r] = v.y;
            As[dq * 4 + 2][r] = v.z;
            As[dq * 4 + 3][r] = v.w;
        }
    }

    float best_sc[8];
    int   best_ix[8];
#pragma unroll
    for (int i = 0; i < 8; ++i) { best_sc[i] = 3.4e38f; best_ix[i] = 0; }

    const float4* w4 = (const float4*)weight;

    for (int chunk = 0; chunk < NCHUNK; ++chunk) {
        float acc[8][8];
#pragma unroll
        for (int i = 0; i < 8; ++i)
#pragma unroll
            for (int j = 0; j < 8; ++j) acc[i][j] = 0.f;

        for (int sub = 0; sub < NSUB; ++sub) {
            __syncthreads();   // previous compute done before Bs overwrite
            {
                // thread t stages code (chunk*256 + t), dims [sub*32, sub*32+32)
                int gk = chunk * BN + tid;
#pragma unroll
                for (int j = 0; j < BK / 4; ++j) {       // 8 float4 loads
                    float4 v = w4[(size_t)gk * D4 + sub * (BK / 4) + j];
                    Bs[j * 4 + 0][tid] = v.x;            // lane->consecutive col: no conflict
                    Bs[j * 4 + 1][tid] = v.y;
                    Bs[j * 4 + 2][tid] = v.z;
                    Bs[j * 4 + 3][tid] = v.w;
                }
            }
            __syncthreads();

            const int dbase = sub * BK;
#pragma unroll 8
            for (int dd = 0; dd < BK; ++dd) {
                float4 a0 = *(const float4*)&As[dbase + dd][row_grp * 8];
                float4 a1 = *(const float4*)&As[dbase + dd][row_grp * 8 + 4];
                float4 b0 = *(const float4*)&Bs[dd][code_grp * 8];
                float4 b1 = *(const float4*)&Bs[dd][code_grp * 8 + 4];
                float a[8] = {a0.x, a0.y, a0.z, a0.w, a1.x, a1.y, a1.z, a1.w};
                float b[8] = {b0.x, b0.y, b0.z, b0.w, b1.x, b1.y, b1.z, b1.w};
#pragma unroll
                for (int i = 0; i < 8; ++i)
#pragma unroll
                    for (int j = 0; j < 8; ++j)
                        acc[i][j] += a[i] * b[j];
            }
        }

        // chunk epilogue: scores = sqr[k] - 2*dot, running lexicographic argmin
#pragma unroll
        for (int j = 0; j < 8; ++j) {
            int gk   = chunk * BN + code_grp * 8 + j;
            float sq = sqr[gk];
#pragma unroll
            for (int i = 0; i < 8; ++i) {
                float s = sq - 2.f * acc[i][j];
                if (s < best_sc[i] || (s == best_sc[i] && gk < best_ix[i])) {
                    best_sc[i] = s;
                    best_ix[i] = gk;
                }
            }
        }
    }

    // ---- cross-thread argmin per row (over 32 code groups) ----
#pragma unroll
    for (int i = 0; i < 8; ++i) {
        int r = row_grp * 8 + i;
        red_sc[r][code_grp] = best_sc[i];
        red_ix[r][code_grp] = best_ix[i];
    }
    __syncthreads();
    if (tid < BM) {
        float bs = red_sc[tid][0];
        int   bi = red_ix[tid][0];
#pragma unroll
        for (int g = 1; g < 32; ++g) {
            float s  = red_sc[tid][g];
            int   ix = red_ix[tid][g];
            if (s < bs || (s == bs && ix < bi)) { bs = s; bi = ix; }
        }
        fin_ix[tid] = bi;
        out[IDX_OFF + row0 + tid] = (float)bi;   // indices as float32
    }
    __syncthreads();

    // ---- gather weight[best] -> values and vectors (coalesced float4) ----
    float4* out4 = (float4*)out;
#pragma unroll
    for (int k = 0; k < (BM * D4) / 256; ++k) {   // 16 iters
        int i = tid + k * 256;
        int r = i >> 6;          // D4 = 64
        int q = i & 63;
        float4 v = w4[(size_t)fin_ix[r] * D4 + q];
        size_t o = (size_t)(row0 + r) * D4 + q;
        out4[VAL_OFF / 4 + o] = v;
        out4[VEC_OFF / 4 + o] = v;
    }
}

extern "C" void kernel_launch(void* const* d_in, const int* in_sizes, int n_in,
                              void* d_out, int out_size, void* d_ws, size_t ws_size,
                              hipStream_t stream) {
    const float* input  = (const float*)d_in[0];   // [64,32,32,256] f32
    const float* weight = (const float*)d_in[1];   // [1024,256] f32
    float* out = (float*)d_out;
    float* sqr = (float*)d_ws;                     // 4 KB scratch

    vq_sqr_kernel<<<KC / 256, 256, 0, stream>>>(weight, sqr);
    vq_main_kernel<<<N_TOK / BM, 256, 0, stream>>>(input, weight, sqr, out);
}